// Round 2
// baseline (234.071 us; speedup 1.0000x reference)
//
#include <hip/hip_runtime.h>

// Problem constants
#define B_ 64
#define T_ 512
#define D_ 1024
#define S_ 1024
#define U_ 10
#define CHUNKS_ 32              // t-chunks per batch row
#define TC_ 16                  // t's per chunk / block
#define NBLK_ (B_ * CHUNKS_)    // 2048 blocks

typedef float f32x2 __attribute__((ext_vector_type(2)));
typedef float f32x4 __attribute__((ext_vector_type(4)));

// workspace layout (in floats)
static constexpr int WS_PMZ = 0;                 // [2048][2] per-block (m, Z)
static constexpr int WS_E   = NBLK_ * 2;         // [64][512] raw e values
static constexpr int WS_PV  = WS_E + B_ * T_;    // [2048][1024] partial weighted sums

// ---------------------------------------------------------------------------
// DPP wave64 sum. wave_sum63 leaves the total in lane 63 (no broadcast);
// wave_sum_uniform broadcasts via readlane.
// ---------------------------------------------------------------------------
template <int CTRL>
__device__ __forceinline__ float dpp_add(float x) {
    int yi = __builtin_amdgcn_update_dpp(0, __float_as_int(x), CTRL, 0xf, 0xf, true);
    return x + __int_as_float(yi);
}

__device__ __forceinline__ float wave_sum63(float x) {
    x = dpp_add<0x111>(x);   // row_shr:1
    x = dpp_add<0x112>(x);   // row_shr:2
    x = dpp_add<0x114>(x);   // row_shr:4
    x = dpp_add<0x118>(x);   // row_shr:8
    x = dpp_add<0x142>(x);   // row_bcast15
    x = dpp_add<0x143>(x);   // row_bcast31 -> lane 63 = total
    return x;
}

__device__ __forceinline__ float wave_sum_uniform(float x) {
    return __int_as_float(__builtin_amdgcn_readlane(__float_as_int(wave_sum63(x)), 63));
}

__device__ __forceinline__ float uload(const float* p) {
    return __int_as_float(__builtin_amdgcn_readfirstlane(__float_as_int(*p)));
}
__device__ __forceinline__ float uniformf(float x) {
    return __int_as_float(__builtin_amdgcn_readfirstlane(__float_as_int(x)));
}

__device__ __forceinline__ f32x2 pk_fma(f32x2 a, f32x2 b, f32x2 c) {
#if __has_builtin(__builtin_elementwise_fma)
    return __builtin_elementwise_fma(a, b, c);
#else
    return a * b + c;
#endif
}

// ---------------------------------------------------------------------------
// K1: 2048 blocks = 64 b x 32 chunks of 16 t. 4 waves/block; wave w owns
// d-range [256w, 256w+256), lane owns 4 contiguous d (one float4).
// Low VGPR (~110) -> 16 waves/CU for latency hiding.
//   dot phase : per t, partial dot over wave's 256 d -> DPP reduce -> LDS pmat
//   e phase   : 16 threads finish e (cross-wave sum + tanh + W2)
//   v phase   : online softmax; a re-read from L2/L3 (fully cache-resident)
// ---------------------------------------------------------------------------
__global__ __launch_bounds__(256, 4) void k1_main(const float* __restrict__ a,
                                                  const float* __restrict__ s_prev,
                                                  const float* __restrict__ W1,
                                                  const float* __restrict__ b1,
                                                  const float* __restrict__ W2,
                                                  const float* __restrict__ b2,
                                                  float* __restrict__ ws) {
    const int blk  = blockIdx.x;
    const int b    = blk >> 5;
    const int p    = blk & 31;
    const int tid  = threadIdx.x;
    const int wave = tid >> 6;
    const int lane = tid & 63;
    const int d4   = tid * 4;   // = wave*256 + lane*4

    __shared__ float pmat[4][TC_][U_];
    __shared__ __align__(16) float esh[TC_];

    // ---- Phase A (wave 0 only): c[u] = s_prev[b]·W1[D:,u] + b1[u] ----
    float c[U_], w2v[U_], b2s = 0.f;
    if (wave == 0) {
        float cacc[U_];
#pragma unroll
        for (int u = 0; u < U_; u++) cacc[u] = 0.f;
#pragma unroll
        for (int r = 0; r < 4; r++) {
            const f32x4 s4 = *(const f32x4*)(s_prev + b * S_ + r * 256 + lane * 4);
            const float svv[4] = {s4.x, s4.y, s4.z, s4.w};
#pragma unroll
            for (int i = 0; i < 4; i++) {
                const int s = r * 256 + lane * 4 + i;
                const float* wp = W1 + (size_t)(D_ + s) * U_;
#pragma unroll
                for (int h = 0; h < 5; h++) {
                    f32x2 t2 = *(const f32x2*)(wp + 2 * h);
                    cacc[2 * h]     += svv[i] * t2.x;
                    cacc[2 * h + 1] += svv[i] * t2.y;
                }
            }
        }
#pragma unroll
        for (int u = 0; u < U_; u++)
            c[u] = uniformf(wave_sum_uniform(cacc[u]) + uload(b1 + u));
#pragma unroll
        for (int u = 0; u < U_; u++) w2v[u] = uload(W2 + u);
        b2s = uload(b2);
    }

    // ---- W1 fragment for this lane's 4 d's, packed as d-pairs ----
    f32x2 w1A[U_], w1B[U_];   // 40 VGPRs
    {
        float wbuf[4][U_];
#pragma unroll
        for (int i = 0; i < 4; i++) {
            const float* wp = W1 + (size_t)(d4 + i) * U_;
#pragma unroll
            for (int h = 0; h < 5; h++) {
                f32x2 t2 = *(const f32x2*)(wp + 2 * h);
                wbuf[i][2 * h]     = t2.x;
                wbuf[i][2 * h + 1] = t2.y;
            }
        }
#pragma unroll
        for (int u = 0; u < U_; u++) {
            w1A[u] = f32x2{wbuf[0][u], wbuf[1][u]};
            w1B[u] = f32x2{wbuf[2][u], wbuf[3][u]};
        }
    }

    const int t0 = p * TC_;
    const float* abase = a + ((size_t)(b * T_ + t0)) * D_ + d4;

    // ---- dot phase: 4-deep prefetch rotation over 16 t ----
    auto dot_step = [&](const f32x4 av, int t) {
        f32x2 acc[U_];
#pragma unroll
        for (int u = 0; u < U_; u++)
            acc[u] = pk_fma(av.hi, w1B[u], av.lo * w1A[u]);
        float h[U_];
#pragma unroll
        for (int u = 0; u < U_; u++) h[u] = wave_sum63(acc[u].x + acc[u].y);
        if (lane == 63) {
#pragma unroll
            for (int u = 0; u < U_; u++) pmat[wave][t][u] = h[u];
        }
    };

    {
        f32x4 av0 = *(const f32x4*)(abase + 0 * D_);
        f32x4 av1 = *(const f32x4*)(abase + 1 * D_);
        f32x4 av2 = *(const f32x4*)(abase + 2 * D_);
        f32x4 av3 = *(const f32x4*)(abase + 3 * D_);
#pragma unroll
        for (int g = 0; g < 4; g++) {
            dot_step(av0, 4 * g + 0);
            if (g < 3) av0 = *(const f32x4*)(abase + (size_t)(4 * g + 4) * D_);
            dot_step(av1, 4 * g + 1);
            if (g < 3) av1 = *(const f32x4*)(abase + (size_t)(4 * g + 5) * D_);
            dot_step(av2, 4 * g + 2);
            if (g < 3) av2 = *(const f32x4*)(abase + (size_t)(4 * g + 6) * D_);
            dot_step(av3, 4 * g + 3);
            if (g < 3) av3 = *(const f32x4*)(abase + (size_t)(4 * g + 7) * D_);
        }
    }

    __syncthreads();

    // ---- e phase: threads 0..15 (wave 0) each finish one t ----
    if (tid < TC_) {
        const int t = tid;
        float e = b2s;
#pragma unroll
        for (int u = 0; u < U_; u++) {
            float x = pmat[0][t][u] + pmat[1][t][u] + pmat[2][t][u] + pmat[3][t][u] + c[u];
            // tanh(x) = 1 - 2/(e^{2x}+1); exp2 saturates -> exact +-1 tails
            float ex = exp2f(x * 2.8853900817779268f);
            float th = 1.f - 2.f * __builtin_amdgcn_rcpf(ex + 1.f);
            e += th * w2v[u];
        }
        e = fmaxf(e, 0.f);
        esh[t] = e;
        ws[WS_E + b * T_ + t0 + t] = e;
    }
    __syncthreads();

    // ---- v phase: online softmax over 16 t; a re-read (L2/L3-resident) ----
    const f32x4 e0 = *(const f32x4*)&esh[0];
    const f32x4 e1 = *(const f32x4*)&esh[4];
    const f32x4 e2 = *(const f32x4*)&esh[8];
    const f32x4 e3 = *(const f32x4*)&esh[12];
    const float ev[TC_] = {e0.x, e0.y, e0.z, e0.w, e1.x, e1.y, e1.z, e1.w,
                           e2.x, e2.y, e2.z, e2.w, e3.x, e3.y, e3.z, e3.w};

    float m = -1e30f, Z = 0.f;
    f32x2 vlo = f32x2{0.f, 0.f}, vhi = f32x2{0.f, 0.f};

    auto v_step = [&](const f32x4 av, float e) {
        if (e > m) {
            float sc = exp2f((m - e) * 1.4426950408889634f);
            Z = Z * sc + 1.f;
            f32x2 scv = {sc, sc};
            vlo = pk_fma(vlo, scv, av.lo);
            vhi = pk_fma(vhi, scv, av.hi);
            m = e;
        } else {
            float w = exp2f((e - m) * 1.4426950408889634f);
            Z += w;
            f32x2 wv = {w, w};
            vlo = pk_fma(wv, av.lo, vlo);
            vhi = pk_fma(wv, av.hi, vhi);
        }
    };

    {
        f32x4 av0 = *(const f32x4*)(abase + 0 * D_);
        f32x4 av1 = *(const f32x4*)(abase + 1 * D_);
        f32x4 av2 = *(const f32x4*)(abase + 2 * D_);
        f32x4 av3 = *(const f32x4*)(abase + 3 * D_);
#pragma unroll
        for (int g = 0; g < 4; g++) {
            v_step(av0, ev[4 * g + 0]);
            if (g < 3) av0 = *(const f32x4*)(abase + (size_t)(4 * g + 4) * D_);
            v_step(av1, ev[4 * g + 1]);
            if (g < 3) av1 = *(const f32x4*)(abase + (size_t)(4 * g + 5) * D_);
            v_step(av2, ev[4 * g + 2]);
            if (g < 3) av2 = *(const f32x4*)(abase + (size_t)(4 * g + 6) * D_);
            v_step(av3, ev[4 * g + 3]);
            if (g < 3) av3 = *(const f32x4*)(abase + (size_t)(4 * g + 7) * D_);
        }
    }

    // ---- epilogue: each wave owns its d-slice; m/Z identical across waves ----
    f32x4 o;
    o.lo = vlo;
    o.hi = vhi;
    ((f32x4*)(ws + WS_PV))[blk * 256 + tid] = o;
    if (tid == 0) { ws[WS_PMZ + blk * 2] = m; ws[WS_PMZ + blk * 2 + 1] = Z; }
}

// ---------------------------------------------------------------------------
// K2: final combine per batch (32 partials) -> context + scores
// ---------------------------------------------------------------------------
__global__ __launch_bounds__(256) void k2_final(const float* __restrict__ ws,
                                                float* __restrict__ out) {
    const int b = blockIdx.x;
    const int tid = threadIdx.x;

    float pm[CHUNKS_], pz[CHUNKS_];
    float mb = -1e30f;
#pragma unroll
    for (int p = 0; p < CHUNKS_; p++) {
        pm[p] = ws[WS_PMZ + (b * CHUNKS_ + p) * 2];
        pz[p] = ws[WS_PMZ + (b * CHUNKS_ + p) * 2 + 1];
        mb = fmaxf(mb, pm[p]);
    }
    float f[CHUNKS_], Z = 0.f;
#pragma unroll
    for (int p = 0; p < CHUNKS_; p++) { f[p] = __expf(pm[p] - mb); Z += f[p] * pz[p]; }
    const float rz = 1.f / Z;

    f32x4 o = f32x4{0.f, 0.f, 0.f, 0.f};
#pragma unroll
    for (int p = 0; p < CHUNKS_; p++) {
        f32x4 t = ((const f32x4*)(ws + WS_PV))[(b * CHUNKS_ + p) * 256 + tid];
        o += f[p] * t;
    }
    o *= rz;
    ((f32x4*)out)[b * 256 + tid] = o;

    for (int t = tid; t < T_; t += 256) {
        out[B_ * D_ + b * T_ + t] = __expf(ws[WS_E + b * T_ + t] - mb) * rz;
    }
}

// ---------------------------------------------------------------------------
extern "C" void kernel_launch(void* const* d_in, const int* in_sizes, int n_in,
                              void* d_out, int out_size, void* d_ws, size_t ws_size,
                              hipStream_t stream) {
    const float* a      = (const float*)d_in[0];
    const float* s_prev = (const float*)d_in[1];
    const float* W1     = (const float*)d_in[2];
    const float* b1     = (const float*)d_in[3];
    const float* W2     = (const float*)d_in[4];
    const float* b2     = (const float*)d_in[5];
    float* out = (float*)d_out;
    float* ws  = (float*)d_ws;

    k1_main<<<dim3(NBLK_), dim3(256), 0, stream>>>(a, s_prev, W1, b1, W2, b2, ws);
    k2_final<<<dim3(B_), dim3(256), 0, stream>>>(ws, out);
}